// Round 20
// baseline (263.498 us; speedup 1.0000x reference)
//
#include <hip/hip_runtime.h>
#include <cstdint>
#include <cstddef>

#define HN    4096
#define TT    128
#define NIN   1024
#define NOUTC 256
#define NWGH  64            // hidden WGs in k_loopA, 64 columns each
#define NWGO  4             // output WGs in k_loopA, 64 columns each
#define NWGT  (NWGH + NWGO)
#define NRB   64            // row-bands in k_pre colsum (64 rows each)
#define S_A   4             // steps simulated by k_loopA (loopB absorbs step 4 adaptively)

// -------- K1: eff = recurrent*binary with zeroed diagonal (mask==ones-eye is
// structural: skip the 64MB mask read) + per-band column partials + zero span
__global__ __launch_bounds__(256) void k_pre(
    const float4* __restrict__ r4,
    const float4* __restrict__ b4, float4* __restrict__ e4,
    double* __restrict__ colP, unsigned* __restrict__ zbase, int zwords)
{
    const int chunk = blockIdx.x;      // 0..3   (1024 cols each)
    const int band  = blockIdx.y;      // 0..63  (64 rows each)
    const int tid   = threadIdx.x;
    if (chunk == 0 && band == 0) {
        for (int i = tid; i < zwords; i += 256) zbase[i] = 0u;
    }
    const int col4 = chunk * 256 + tid;          // float4 index within a row
    double a0 = 0.0, a1 = 0.0, a2 = 0.0, a3 = 0.0;
    for (int r = 0; r < 64; ++r) {
        const int row = band * 64 + r;
        const size_t idx = (size_t)row * (HN / 4) + col4;
        float4 a = r4[idx], c = b4[idx];
        float4 o;
        o.x = a.x * c.x;
        o.y = a.y * c.y;
        o.z = a.z * c.z;
        o.w = a.w * c.w;
        if (col4 == (row >> 2)) {                // diagonal element lives here
            const int comp = row & 3;
            if      (comp == 0) o.x = 0.f;
            else if (comp == 1) o.y = 0.f;
            else if (comp == 2) o.z = 0.f;
            else                o.w = 0.f;
        }
        e4[idx] = o;
        a0 += (double)o.x; a1 += (double)o.y; a2 += (double)o.z; a3 += (double)o.w;
    }
    double* cp = colP + (size_t)band * HN + (size_t)col4 * 4;
    cp[0] = a0; cp[1] = a1; cp[2] = a2; cp[3] = a3;
}

// ---------------- K2: fused transpose (wT) + colvO (w_out row sums) ---------
__global__ __launch_bounds__(256) void k_misc(const float* __restrict__ wout,
                                              float* __restrict__ wT,
                                              double* __restrict__ colvO)
{
    const int bx = blockIdx.x;
    if (bx < 256) {
        __shared__ float tile[64][65];
        const int h0 = (bx & 63) * 64;
        const int o0 = (bx >> 6) * 64;
        const int lx = threadIdx.x & 63, ly = threadIdx.x >> 6;  // ly 0..3
        #pragma unroll
        for (int i = 0; i < 16; ++i) {
            int o = ly + 4 * i;
            tile[o][lx] = wout[(size_t)(o0 + o) * HN + h0 + lx];
        }
        __syncthreads();
        #pragma unroll
        for (int i = 0; i < 16; ++i) {
            int h = ly + 4 * i;
            wT[(size_t)(h0 + h) * NOUTC + o0 + lx] = tile[lx][h];
        }
    } else {
        // colvO: blocks 256..319, each 4 rows of w_out (wave per row)
        const int b2 = bx - 256;                 // 0..63
        const int wv = threadIdx.x >> 6, lane = threadIdx.x & 63;
        const int o = b2 * 4 + wv;
        double s = 0.0;
        const float* p = wout + (size_t)o * HN + lane;
        #pragma unroll 8
        for (int j = 0; j < 64; ++j) s += (double)p[(size_t)j * 64];
        #pragma unroll
        for (int d = 1; d < 64; d <<= 1) {
            union { double d2; long long l; } u; u.d2 = s;
            u.l = __shfl_xor(u.l, d, 64);
            s += u.d2;
        }
        if (lane == 0) colvO[o] = s;
    }
}

// ---------------- K3: ff[t][h] = sum_i x[t][i]*w_fc1[h][i]  (fp64 acc) ------
__global__ __launch_bounds__(256) void k_ff(const float* __restrict__ x,
                                            const float* __restrict__ w,
                                            double* __restrict__ ff)
{
    __shared__ float xs[16][36];
    __shared__ float wsT[32][73];
    const int h0 = blockIdx.x * 64;
    const int t0 = blockIdx.y * 16;
    const int tid = threadIdx.x;
    const int tq = tid >> 5, hq = tid & 31;   // tq 0..7, hq 0..31
    double acc00 = 0.0, acc01 = 0.0, acc10 = 0.0, acc11 = 0.0;
    for (int kc = 0; kc < NIN; kc += 32) {
        __syncthreads();
        #pragma unroll
        for (int s2 = 0; s2 < 2; ++s2) {
            int e = tid + s2 * 256; int t = e >> 5, k = e & 31;
            xs[t][k] = x[(size_t)(t0 + t) * NIN + kc + k];
        }
        #pragma unroll
        for (int s2 = 0; s2 < 8; ++s2) {
            int e = tid + s2 * 256; int h = e >> 5, k = e & 31;
            wsT[k][h] = w[(size_t)(h0 + h) * NIN + kc + k];
        }
        __syncthreads();
        #pragma unroll 8
        for (int k = 0; k < 32; ++k) {
            double a0 = (double)xs[tq][k];
            double a1 = (double)xs[tq + 8][k];
            double b0 = (double)wsT[k][hq];
            double b1 = (double)wsT[k][hq + 32];
            acc00 += a0 * b0; acc01 += a0 * b1;
            acc10 += a1 * b0; acc11 += a1 * b1;
        }
    }
    ff[(size_t)(t0 + tq) * HN + h0 + hq]          = acc00;
    ff[(size_t)(t0 + tq) * HN + h0 + hq + 32]     = acc01;
    ff[(size_t)(t0 + tq + 8) * HN + h0 + hq]      = acc10;
    ff[(size_t)(t0 + tq + 8) * HN + h0 + hq + 32] = acc11;
}

// ---------------- K3c: reduce colP -> colvH (deterministic band order) ------
__global__ __launch_bounds__(256) void k_colred(const double* __restrict__ colP,
                                                double* __restrict__ colvH)
{
    const int h = blockIdx.x * 256 + threadIdx.x;   // grid 16
    double s = 0.0;
    #pragma unroll
    for (int rb = 0; rb < NRB; ++rb) s += colP[(size_t)rb * HN + h];
    colvH[h] = s;
}

// ---------------- K3d: saturation predicate for steps S_A..TT-1 -------------
__global__ __launch_bounds__(256) void k_sat(const double* __restrict__ ff,
                                             const double* __restrict__ colvH,
                                             unsigned* __restrict__ satFail)
{
    __shared__ int s_ok[4];
    const int t = S_A + blockIdx.x;
    const int tid = threadIdx.x;
    bool ok = true;
    #pragma unroll
    for (int i = 0; i < 16; ++i) {
        const int h = tid + 256 * i;
        ok = ok && ((ff[(size_t)t * HN + h] + 0.1 * colvH[h]) >= 0.5);
    }
    unsigned long long b = __ballot(ok);
    if ((tid & 63) == 0) s_ok[tid >> 6] = (b == ~0ULL) ? 1 : 0;
    __syncthreads();
    if (tid == 0) {
        if (!(s_ok[0] & s_ok[1] & s_ok[2] & s_ok[3])) atomicOr(satFail, 1u);
    }
}

// ---------------- K4a: 68-WG transient scan, steps 0..S_A-1 -----------------
__global__ __launch_bounds__(1024) void k_loopA(
    const float* __restrict__ eff, const float* __restrict__ wT,
    const double* __restrict__ ff, const float* __restrict__ tau,
    const double* __restrict__ colvH, const double* __restrict__ colvO,
    unsigned long long* spk, unsigned long long* bar, float* out,
    double* __restrict__ hmS, unsigned* __restrict__ flagsS,
    unsigned* __restrict__ AS, unsigned* __restrict__ N0S, unsigned* __restrict__ N1S,
    double* __restrict__ omS, unsigned* __restrict__ oflagsS)
{
    __shared__ unsigned short s_list[2048];
    __shared__ double s_part[16][64];
    __shared__ int s_kbc;

    const int wg = blockIdx.x;
    const int tid = threadIdx.x;
    const int wv = tid >> 6;
    const int lane = tid & 63;
    const bool isH = (wg < NWGH);

    const size_t rstride = isH ? (size_t)HN : (size_t)NOUTC;
    const int base0 = isH ? wg * 64 : (wg - NWGH) * 64;
    const float* gbase = (isH ? eff : wT) + base0 + lane;
    const int c = base0 + lane;            // wave-0 update column

    double colv = 0.0, hm = 0.0, om = 0.0, ffv = 0.0;
    float tauv = 0.f;
    int sp1 = 0, sp2 = 0, osp = 0;
    unsigned curA = 0, curN0 = 0, curN1 = 0, naccr = 0;
    if (wv == 0) {
        if (isH) { colv = colvH[c]; tauv = tau[c]; ffv = ff[c]; }
        else     { colv = colvO[c]; }
    }
    unsigned lsense = 0;
    int kcur = 0;
    unsigned myCnt = 0;

    for (int it = 0; it <= S_A; ++it) {
        const bool active = isH ? (it < S_A) : (it > 0);
        if (active) {
            const int k = kcur;
            const bool gspk = (k <= HN / 2);
            const int nlist = gspk ? k : HN - k;
            if (nlist > 0) {
                if (tid < 64) {
                    unsigned long long w = __hip_atomic_load(
                        &spk[(size_t)((it + 1) & 1) * 64 + lane],
                        __ATOMIC_RELAXED, __HIP_MEMORY_SCOPE_AGENT);
                    unsigned long long myw = gspk ? w : ~w;
                    int cnt = __popcll(myw);
                    int incl = cnt;
                    #pragma unroll
                    for (int d = 1; d < 64; d <<= 1) {
                        int o = __shfl_up(incl, d, 64);
                        if (lane >= d) incl += o;
                    }
                    int b = incl - cnt;
                    while (myw) {
                        int bp = __builtin_ctzll(myw);
                        s_list[b++] = (unsigned short)(lane * 64 + bp);
                        myw &= myw - 1;
                    }
                }
                __syncthreads();
                // 8-deep independent loads per iteration (latency hiding)
                double acc = 0.0;
                int idx = wv;
                for (; idx + 112 < nlist; idx += 128) {
                    const float v0 = gbase[(size_t)s_list[idx      ] * rstride];
                    const float v1 = gbase[(size_t)s_list[idx + 16 ] * rstride];
                    const float v2 = gbase[(size_t)s_list[idx + 32 ] * rstride];
                    const float v3 = gbase[(size_t)s_list[idx + 48 ] * rstride];
                    const float v4 = gbase[(size_t)s_list[idx + 64 ] * rstride];
                    const float v5 = gbase[(size_t)s_list[idx + 80 ] * rstride];
                    const float v6 = gbase[(size_t)s_list[idx + 96 ] * rstride];
                    const float v7 = gbase[(size_t)s_list[idx + 112] * rstride];
                    acc += (((double)v0 + (double)v1) + ((double)v2 + (double)v3))
                         + (((double)v4 + (double)v5) + ((double)v6 + (double)v7));
                }
                for (; idx < nlist; idx += 16)
                    acc += (double)gbase[(size_t)s_list[idx] * rstride];
                s_part[wv][lane] = acc;
                __syncthreads();
            }
            if (wv == 0) {
                double ssum = 0.0;
                if (nlist > 0) {
                    #pragma unroll
                    for (int p = 0; p < 16; ++p) ssum += s_part[p][lane];
                }
                double drive = gspk ? ssum : (colv - ssum);
                if (isH) {
                    const int t = it;
                    double cur = ffv + 0.1 * drive;
                    hm = hm * (double)tauv * (double)(1 - sp1) + cur;
                    int s = (hm >= 0.5) ? 1 : 0;
                    int n = s + sp1 + sp2;
                    sp2 = sp1; sp1 = s;
                    naccr += (unsigned)n;
                    unsigned bit = 1u << (t & 31);
                    if (s)     curA  |= bit;
                    if (n & 1) curN0 |= bit;
                    if (n & 2) curN1 |= bit;
                    unsigned long long ball = __ballot(s != 0);
                    if (lane == 0) {
                        __hip_atomic_store(&spk[(size_t)(t & 1) * 64 + wg], ball,
                                           __ATOMIC_RELEASE, __HIP_MEMORY_SCOPE_AGENT);
                        __threadfence();
                        myCnt = (unsigned)__popcll(ball);
                    }
                    ffv = ff[(size_t)(it + 1) * HN + c];  // prefetch (it+1<=S_A valid)
                } else {
                    const int t = it - 1;
                    om = om * 0.96 * (double)(1 - osp) + drive;
                    osp = (om >= 0.5) ? 1 : 0;
                    out[(size_t)t * NOUTC + c] = osp ? 1.0f : 0.0f;
                }
            }
        }
        if (it < S_A) {
            __syncthreads();
            if (tid == 0) {
                unsigned s = lsense ^ 1u;
                lsense = s;
                unsigned cntW = isH ? myCnt : 0u;
                unsigned long long prev = __hip_atomic_fetch_add(
                    &bar[0], (1ULL << 32) + (unsigned long long)cntW,
                    __ATOMIC_ACQ_REL, __HIP_MEMORY_SCOPE_AGENT);
                unsigned long long v;
                if ((unsigned)(prev >> 32) == NWGT - 1u) {
                    unsigned ktot = (unsigned)(prev & 0xffffffffULL) + cntW;
                    __hip_atomic_store(&bar[0], 0ULL, __ATOMIC_RELAXED, __HIP_MEMORY_SCOPE_AGENT);
                    v = ((unsigned long long)ktot << 1) | (unsigned long long)s;
                    __hip_atomic_store(&bar[1], v, __ATOMIC_RELEASE, __HIP_MEMORY_SCOPE_AGENT);
                } else {
                    int budget = 1 << 17;
                    for (;;) {
                        v = __hip_atomic_load(&bar[1], __ATOMIC_ACQUIRE, __HIP_MEMORY_SCOPE_AGENT);
                        if ((unsigned)(v & 1ULL) == s) break;
                        if (--budget == 0) break;
                    }
                }
                s_kbc = (int)(v >> 1);
            }
            __syncthreads();
            kcur = s_kbc;
        }
    }
    if (wv == 0) {
        if (isH) {
            hmS[c] = hm;
            flagsS[c] = (unsigned)sp1 | ((unsigned)sp2 << 1) | (naccr << 2);
            AS[c] = curA; N0S[c] = curN0; N1S[c] = curN1;
        } else {
            omS[c] = om;
            oflagsS[c] = (unsigned)osp;
        }
    }
}

// ---------------- K4b: single-WG adaptive scan, steps S_A..127 --------------
// Runs the general step until the OBSERVED spike count hits HN (all-spike) with
// satFail==0; from that step t_sw the closed form is exact (induction via the
// verified predicate). With S_A=4 this absorbs the ~6-row-complement step 4
// cheaply, saving one full grid-barrier step in loopA.
__global__ __launch_bounds__(1024) void k_loopB(
    const float* __restrict__ eff, const float* __restrict__ wT,
    const double* __restrict__ ff, const float* __restrict__ tau,
    const double* __restrict__ colvH, const double* __restrict__ colvO,
    const unsigned long long* __restrict__ spk,
    const double* __restrict__ hmS, const unsigned* __restrict__ flagsS,
    const unsigned* __restrict__ AS, const unsigned* __restrict__ N0S,
    const unsigned* __restrict__ N1S,
    const double* __restrict__ omS, const unsigned* __restrict__ oflagsS,
    const unsigned* __restrict__ satFail,
    unsigned* __restrict__ AwP, unsigned* __restrict__ N0wP,
    unsigned* __restrict__ N1wP, unsigned* __restrict__ Nacc,
    float* __restrict__ out)
{
    __shared__ unsigned long long s_words[64];
    __shared__ unsigned short s_list[2048];

    const int tid = threadIdx.x;
    const int wv = tid >> 6, lane = tid & 63;

    // ---- load state (always) ----
    double hm[4], colv[4], tauv[4];
    unsigned curA[4], curN0[4], curN1[4], nacc[4];
    int sp1[4], sp2[4];
    #pragma unroll
    for (int p = 0; p < 4; ++p) {
        const int c = tid + 1024 * p;
        hm[p] = hmS[c];
        unsigned f = flagsS[c];
        sp1[p] = f & 1; sp2[p] = (f >> 1) & 1; nacc[p] = f >> 2;
        curA[p] = AS[c]; curN0[p] = N0S[c]; curN1[p] = N1S[c];
        tauv[p] = (double)tau[c];
        colv[p] = colvH[c];
    }
    double om = 0.0, colO = 0.0;
    int osp = 0;
    if (tid < NOUTC) {
        om = omS[tid]; osp = (int)(oflagsS[tid] & 1u);
        colO = colvO[tid];
    }

    // seed spikes from loopA's last step (parity (S_A-1)&1)
    if (tid < 64) s_words[tid] = spk[(size_t)((S_A - 1) & 1) * 64 + tid];
    __syncthreads();
    int kprev;
    {
        int v = __popcll(s_words[lane]);
        #pragma unroll
        for (int d = 1; d < 64; d <<= 1) v += __shfl_xor(v, d, 64);
        kprev = v;
    }
    bool gprev = (kprev <= HN / 2);
    int nprev = gprev ? kprev : HN - kprev;
    const bool satOK = (satFail[0] == 0u);
    bool allspike = (kprev == HN);

    if (nprev > 0) {
        if (tid < 64) {
            unsigned long long myw = gprev ? s_words[tid] : ~s_words[tid];
            int cnt = __popcll(myw), incl = cnt;
            #pragma unroll
            for (int d = 1; d < 64; d <<= 1) { int o = __shfl_up(incl, d, 64); if (lane >= d) incl += o; }
            int b = incl - cnt;
            while (myw) { int bp = __builtin_ctzll(myw); s_list[b++] = (unsigned short)(tid * 64 + bp); myw &= myw - 1; }
        }
        __syncthreads();
    }

    // ---- general loop until observed saturation ----
    int t = S_A;
    while (t < TT && !(satOK && allspike)) {
        double fcur[4];
        #pragma unroll
        for (int p = 0; p < 4; ++p) fcur[p] = ff[(size_t)t * HN + tid + 1024 * p];
        double drv[4];
        if (nprev > 0) {
            double s0 = 0.0, s1 = 0.0, s2 = 0.0, s3 = 0.0;
            for (int idx = 0; idx < nprev; ++idx) {
                const float* rp = eff + (size_t)s_list[idx] * HN + tid;
                s0 += (double)rp[0];
                s1 += (double)rp[1024];
                s2 += (double)rp[2048];
                s3 += (double)rp[3072];
            }
            drv[0] = gprev ? s0 : (colv[0] - s0);
            drv[1] = gprev ? s1 : (colv[1] - s1);
            drv[2] = gprev ? s2 : (colv[2] - s2);
            drv[3] = gprev ? s3 : (colv[3] - s3);
        } else {
            #pragma unroll
            for (int p = 0; p < 4; ++p) drv[p] = gprev ? 0.0 : colv[p];
        }
        int sb[4];
        const unsigned bit = 1u << (t & 31);
        #pragma unroll
        for (int p = 0; p < 4; ++p) {
            double cur = fcur[p] + 0.1 * drv[p];
            hm[p] = hm[p] * tauv[p] * (double)(1 - sp1[p]) + cur;
            sb[p] = (hm[p] >= 0.5) ? 1 : 0;
            int n = sb[p] + sp1[p] + sp2[p];
            sp2[p] = sp1[p]; sp1[p] = sb[p];
            nacc[p] += (unsigned)n;
            if (sb[p]) curA[p] |= bit;
            if (n & 1) curN0[p] |= bit;
            if (n & 2) curN1[p] |= bit;
        }
        if ((t & 31) == 31) {
            const int wq = t >> 5;
            #pragma unroll
            for (int p = 0; p < 4; ++p) {
                const int c = tid + 1024 * p;
                AwP [wq * HN + c] = curA[p];
                N0wP[wq * HN + c] = curN0[p];
                N1wP[wq * HN + c] = curN1[p];
                curA[p] = curN0[p] = curN1[p] = 0u;
            }
        }
        __syncthreads();
        #pragma unroll
        for (int p = 0; p < 4; ++p) {
            unsigned long long b = __ballot(sb[p] != 0);
            if (lane == 0) s_words[16 * p + wv] = b;
        }
        __syncthreads();
        int k;
        {
            int v = __popcll(s_words[lane]);
            #pragma unroll
            for (int d = 1; d < 64; d <<= 1) v += __shfl_xor(v, d, 64);
            k = v;
        }
        const bool gspk = (k <= HN / 2);
        const int nlist = gspk ? k : HN - k;
        if (nlist > 0) {
            if (tid < 64) {
                unsigned long long myw = gspk ? s_words[tid] : ~s_words[tid];
                int cnt = __popcll(myw), incl = cnt;
                #pragma unroll
                for (int d = 1; d < 64; d <<= 1) { int o = __shfl_up(incl, d, 64); if (lane >= d) incl += o; }
                int b2 = incl - cnt;
                while (myw) { int bp = __builtin_ctzll(myw); s_list[b2++] = (unsigned short)(tid * 64 + bp); myw &= myw - 1; }
            }
            __syncthreads();
        }
        if (tid < NOUTC) {
            double so = 0.0;
            for (int idx = 0; idx < nlist; ++idx)
                so += (double)wT[(size_t)s_list[idx] * NOUTC + tid];
            double drv_o = gspk ? so : (colO - so);
            om = om * 0.96 * (double)(1 - osp) + drv_o;
            osp = (om >= 0.5) ? 1 : 0;
            out[(size_t)t * NOUTC + tid] = osp ? 1.0f : 0.0f;
        }
        gprev = gspk; nprev = nlist;
        allspike = (k == HN);
        ++t;
    }

    if (t < TT) {
        // ---- closed-form tail from t_sw = t (sp1[p]==1 for all neurons) ----
        const int t_sw = t;
        const int wq_sw = t_sw >> 5;
        const int off = t_sw & 31;
        const unsigned hiA = 0xFFFFFFFFu << off;
        const unsigned hi1 = (off < 31) ? (0xFFFFFFFFu << (off + 1)) : 0u;
        #pragma unroll
        for (int p = 0; p < 4; ++p) {
            const int c = tid + 1024 * p;
            AwP [wq_sw * HN + c] = curA[p]  | hiA;
            N0wP[wq_sw * HN + c] = curN0[p] | ((unsigned)sp2[p] << off) | hi1;
            N1wP[wq_sw * HN + c] = curN1[p] | hiA;
            for (int wq = wq_sw + 1; wq < 4; ++wq) {
                AwP [wq * HN + c] = 0xFFFFFFFFu;
                N0wP[wq * HN + c] = 0xFFFFFFFFu;
                N1wP[wq * HN + c] = 0xFFFFFFFFu;
            }
            Nacc[c] = nacc[p] + (unsigned)(2 + sp2[p]) + 3u * (unsigned)(TT - 1 - t_sw);
        }
        if (tid < NOUTC) {
            for (int tt = t_sw; tt < TT; ++tt) {
                om = om * 0.96 * (double)(1 - osp) + colO;
                osp = (om >= 0.5) ? 1 : 0;
                out[(size_t)tt * NOUTC + tid] = osp ? 1.0f : 0.0f;
            }
        }
        return;
    }
    #pragma unroll
    for (int p = 0; p < 4; ++p) Nacc[tid + 1024 * p] = nacc[p];
}

// ---------------- K5: rec_out = recurrent + 0.01*(3T - 2N[i] + 2M[i][j]) ----
__global__ __launch_bounds__(256) void k_rec(const float* __restrict__ recur,
    const unsigned* __restrict__ AwP, const unsigned* __restrict__ N0wP,
    const unsigned* __restrict__ N1wP, const unsigned* __restrict__ Nacc,
    float* __restrict__ out)
{
    const int j = blockIdx.x * 256 + threadIdx.x;
    const int i0 = blockIdx.y * 32;
    const unsigned a0 = AwP[0 * HN + j], a1 = AwP[1 * HN + j];
    const unsigned a2 = AwP[2 * HN + j], a3 = AwP[3 * HN + j];
    for (int ii = 0; ii < 32; ++ii) {
        const int i = i0 + ii;
        const unsigned n00 = N0wP[0 * HN + i], n01 = N0wP[1 * HN + i];
        const unsigned n02 = N0wP[2 * HN + i], n03 = N0wP[3 * HN + i];
        const unsigned n10 = N1wP[0 * HN + i], n11 = N1wP[1 * HN + i];
        const unsigned n12 = N1wP[2 * HN + i], n13 = N1wP[3 * HN + i];
        int M = __popc(a0 & n00) + __popc(a1 & n01) + __popc(a2 & n02) + __popc(a3 & n03);
        M += 2 * (__popc(a0 & n10) + __popc(a1 & n11) + __popc(a2 & n12) + __popc(a3 & n13));
        const int D = 3 * TT - 2 * (int)Nacc[i] + 2 * M;
        out[(size_t)i * HN + j] = (float)((double)recur[(size_t)i * HN + j] + 0.01 * (double)D);
    }
}

// ---------------- host ------------------------------------------------------
extern "C" void kernel_launch(void* const* d_in, const int* in_sizes, int n_in,
                              void* d_out, int out_size, void* d_ws, size_t ws_size,
                              hipStream_t stream) {
    const float* x         = (const float*)d_in[0];
    const float* w_fc1     = (const float*)d_in[1];
    const float* w_out     = (const float*)d_in[2];
    const float* recurrent = (const float*)d_in[3];
    const float* tau       = (const float*)d_in[4];
    const float* binary    = (const float*)d_in[6];
    float* out = (float*)d_out;
    float* rec_out = out + (size_t)TT * NOUTC;   // [HN,HN] region of d_out
    float* eff = rec_out;                         // reused as eff_rec scratch

    char* ws = (char*)d_ws;
    size_t off = 0;
    float* wT  = (float*)(ws + off);                 off += (size_t)HN * NOUTC * 4;   // 4MB
    double* ff = (double*)(ws + off);                off += (size_t)TT * HN * 8;      // 4MB
    // zero-span (contiguous): spk, bar(+satFail)
    unsigned long long* spk = (unsigned long long*)(ws + off); off += 2 * 64 * 8;     // 1KB
    unsigned long long* bar = (unsigned long long*)(ws + off); off += 256;
    unsigned* satFail = (unsigned*)((char*)bar + 128);   // inside zeroed bar block
    const int zwords = (int)((2 * 64 * 8 + 256) / 4);
    unsigned* AwP  = (unsigned*)(ws + off);          off += (size_t)4 * HN * 4;       // 64KB
    unsigned* N0wP = (unsigned*)(ws + off);          off += (size_t)4 * HN * 4;
    unsigned* N1wP = (unsigned*)(ws + off);          off += (size_t)4 * HN * 4;
    unsigned* Nacc = (unsigned*)(ws + off);          off += (size_t)HN * 4;
    double* colP   = (double*)(ws + off);            off += (size_t)NRB * HN * 8;     // 2MB
    double* colvH  = (double*)(ws + off);            off += (size_t)HN * 8;           // 32KB
    double* colvO  = (double*)(ws + off);            off += (size_t)NOUTC * 8;        // 2KB
    // A→B handoff state
    double*   hmS    = (double*)(ws + off);          off += (size_t)HN * 8;           // 32KB
    unsigned* flagsS = (unsigned*)(ws + off);        off += (size_t)HN * 4;           // 16KB
    unsigned* AS     = (unsigned*)(ws + off);        off += (size_t)HN * 4;
    unsigned* N0S    = (unsigned*)(ws + off);        off += (size_t)HN * 4;
    unsigned* N1S    = (unsigned*)(ws + off);        off += (size_t)HN * 4;
    double*   omS    = (double*)(ws + off);          off += (size_t)NOUTC * 8;        // 2KB
    unsigned* oflagsS= (unsigned*)(ws + off);        off += (size_t)NOUTC * 4;        // 1KB

    if (ws_size < off) return;  // refuse to corrupt memory if scratch too small

    k_pre<<<dim3(4, 64), dim3(256), 0, stream>>>(
        (const float4*)recurrent, (const float4*)binary,
        (float4*)eff, colP, (unsigned*)spk, zwords);
    k_misc<<<dim3(320), dim3(256), 0, stream>>>(w_out, wT, colvO);
    k_ff<<<dim3(64, 8), dim3(256), 0, stream>>>(x, w_fc1, ff);
    k_colred<<<dim3(16), dim3(256), 0, stream>>>(colP, colvH);
    k_sat<<<dim3(TT - S_A), dim3(256), 0, stream>>>(ff, colvH, satFail);
    k_loopA<<<dim3(NWGT), dim3(1024), 0, stream>>>(eff, wT, ff, tau, colvH, colvO,
                                                   spk, bar, out,
                                                   hmS, flagsS, AS, N0S, N1S, omS, oflagsS);
    k_loopB<<<dim3(1), dim3(1024), 0, stream>>>(eff, wT, ff, tau, colvH, colvO, spk,
                                                hmS, flagsS, AS, N0S, N1S, omS, oflagsS,
                                                satFail, AwP, N0wP, N1wP, Nacc, out);
    k_rec<<<dim3(16, 128), dim3(256), 0, stream>>>(recurrent, AwP, N0wP, N1wP, Nacc,
                                                   rec_out);
}

// Round 21
// 209.161 us; speedup vs baseline: 1.2598x; 1.2598x over previous
//
#include <hip/hip_runtime.h>
#include <cstdint>
#include <cstddef>

#define HN    4096
#define TT    128
#define NIN   1024
#define NOUTC 256
#define NWGH  64            // hidden WGs in k_loopA, 64 columns each
#define NWGO  4             // output WGs in k_loopA, 64 columns each
#define NWGT  (NWGH + NWGO)
#define NRB   64            // row-bands in k_pre colsum (64 rows each)
#define S_A   5             // steps simulated by k_loopA (measured optimum; S_A=4 regressed)

// -------- K1: eff = recurrent*binary with zeroed diagonal (mask==ones-eye is
// structural: skip the 64MB mask read) + per-band column partials + zero span
__global__ __launch_bounds__(256) void k_pre(
    const float4* __restrict__ r4,
    const float4* __restrict__ b4, float4* __restrict__ e4,
    double* __restrict__ colP, unsigned* __restrict__ zbase, int zwords)
{
    const int chunk = blockIdx.x;      // 0..3   (1024 cols each)
    const int band  = blockIdx.y;      // 0..63  (64 rows each)
    const int tid   = threadIdx.x;
    if (chunk == 0 && band == 0) {
        for (int i = tid; i < zwords; i += 256) zbase[i] = 0u;
    }
    const int col4 = chunk * 256 + tid;          // float4 index within a row
    double a0 = 0.0, a1 = 0.0, a2 = 0.0, a3 = 0.0;
    for (int r = 0; r < 64; ++r) {
        const int row = band * 64 + r;
        const size_t idx = (size_t)row * (HN / 4) + col4;
        float4 a = r4[idx], c = b4[idx];
        float4 o;
        o.x = a.x * c.x;
        o.y = a.y * c.y;
        o.z = a.z * c.z;
        o.w = a.w * c.w;
        if (col4 == (row >> 2)) {                // diagonal element lives here
            const int comp = row & 3;
            if      (comp == 0) o.x = 0.f;
            else if (comp == 1) o.y = 0.f;
            else if (comp == 2) o.z = 0.f;
            else                o.w = 0.f;
        }
        e4[idx] = o;
        a0 += (double)o.x; a1 += (double)o.y; a2 += (double)o.z; a3 += (double)o.w;
    }
    double* cp = colP + (size_t)band * HN + (size_t)col4 * 4;
    cp[0] = a0; cp[1] = a1; cp[2] = a2; cp[3] = a3;
}

// ---------------- K2: fused transpose (wT) + colvO (w_out row sums) ---------
__global__ __launch_bounds__(256) void k_misc(const float* __restrict__ wout,
                                              float* __restrict__ wT,
                                              double* __restrict__ colvO)
{
    const int bx = blockIdx.x;
    if (bx < 256) {
        __shared__ float tile[64][65];
        const int h0 = (bx & 63) * 64;
        const int o0 = (bx >> 6) * 64;
        const int lx = threadIdx.x & 63, ly = threadIdx.x >> 6;  // ly 0..3
        #pragma unroll
        for (int i = 0; i < 16; ++i) {
            int o = ly + 4 * i;
            tile[o][lx] = wout[(size_t)(o0 + o) * HN + h0 + lx];
        }
        __syncthreads();
        #pragma unroll
        for (int i = 0; i < 16; ++i) {
            int h = ly + 4 * i;
            wT[(size_t)(h0 + h) * NOUTC + o0 + lx] = tile[lx][h];
        }
    } else {
        // colvO: blocks 256..319, each 4 rows of w_out (wave per row)
        const int b2 = bx - 256;                 // 0..63
        const int wv = threadIdx.x >> 6, lane = threadIdx.x & 63;
        const int o = b2 * 4 + wv;
        double s = 0.0;
        const float* p = wout + (size_t)o * HN + lane;
        #pragma unroll 8
        for (int j = 0; j < 64; ++j) s += (double)p[(size_t)j * 64];
        #pragma unroll
        for (int d = 1; d < 64; d <<= 1) {
            union { double d2; long long l; } u; u.d2 = s;
            u.l = __shfl_xor(u.l, d, 64);
            s += u.d2;
        }
        if (lane == 0) colvO[o] = s;
    }
}

// ---------------- K3: ff[t][h] = sum_i x[t][i]*w_fc1[h][i]  (fp64 acc) ------
__global__ __launch_bounds__(256) void k_ff(const float* __restrict__ x,
                                            const float* __restrict__ w,
                                            double* __restrict__ ff)
{
    __shared__ float xs[16][36];
    __shared__ float wsT[32][73];
    const int h0 = blockIdx.x * 64;
    const int t0 = blockIdx.y * 16;
    const int tid = threadIdx.x;
    const int tq = tid >> 5, hq = tid & 31;   // tq 0..7, hq 0..31
    double acc00 = 0.0, acc01 = 0.0, acc10 = 0.0, acc11 = 0.0;
    for (int kc = 0; kc < NIN; kc += 32) {
        __syncthreads();
        #pragma unroll
        for (int s2 = 0; s2 < 2; ++s2) {
            int e = tid + s2 * 256; int t = e >> 5, k = e & 31;
            xs[t][k] = x[(size_t)(t0 + t) * NIN + kc + k];
        }
        #pragma unroll
        for (int s2 = 0; s2 < 8; ++s2) {
            int e = tid + s2 * 256; int h = e >> 5, k = e & 31;
            wsT[k][h] = w[(size_t)(h0 + h) * NIN + kc + k];
        }
        __syncthreads();
        #pragma unroll 8
        for (int k = 0; k < 32; ++k) {
            double a0 = (double)xs[tq][k];
            double a1 = (double)xs[tq + 8][k];
            double b0 = (double)wsT[k][hq];
            double b1 = (double)wsT[k][hq + 32];
            acc00 += a0 * b0; acc01 += a0 * b1;
            acc10 += a1 * b0; acc11 += a1 * b1;
        }
    }
    ff[(size_t)(t0 + tq) * HN + h0 + hq]          = acc00;
    ff[(size_t)(t0 + tq) * HN + h0 + hq + 32]     = acc01;
    ff[(size_t)(t0 + tq + 8) * HN + h0 + hq]      = acc10;
    ff[(size_t)(t0 + tq + 8) * HN + h0 + hq + 32] = acc11;
}

// ---------------- K3c: reduce colP -> colvH (deterministic band order) ------
__global__ __launch_bounds__(256) void k_colred(const double* __restrict__ colP,
                                                double* __restrict__ colvH)
{
    const int h = blockIdx.x * 256 + threadIdx.x;   // grid 16
    double s = 0.0;
    #pragma unroll
    for (int rb = 0; rb < NRB; ++rb) s += colP[(size_t)rb * HN + h];
    colvH[h] = s;
}

// ---------------- K3d: saturation predicate for steps S_A..TT-1 -------------
__global__ __launch_bounds__(256) void k_sat(const double* __restrict__ ff,
                                             const double* __restrict__ colvH,
                                             unsigned* __restrict__ satFail)
{
    __shared__ int s_ok[4];
    const int t = S_A + blockIdx.x;
    const int tid = threadIdx.x;
    bool ok = true;
    #pragma unroll
    for (int i = 0; i < 16; ++i) {
        const int h = tid + 256 * i;
        ok = ok && ((ff[(size_t)t * HN + h] + 0.1 * colvH[h]) >= 0.5);
    }
    unsigned long long b = __ballot(ok);
    if ((tid & 63) == 0) s_ok[tid >> 6] = (b == ~0ULL) ? 1 : 0;
    __syncthreads();
    if (tid == 0) {
        if (!(s_ok[0] & s_ok[1] & s_ok[2] & s_ok[3])) atomicOr(satFail, 1u);
    }
}

// ---------------- K4a: 68-WG transient scan, steps 0..S_A-1 -----------------
__global__ __launch_bounds__(1024) void k_loopA(
    const float* __restrict__ eff, const float* __restrict__ wT,
    const double* __restrict__ ff, const float* __restrict__ tau,
    const double* __restrict__ colvH, const double* __restrict__ colvO,
    unsigned long long* spk, unsigned long long* bar, float* out,
    double* __restrict__ hmS, unsigned* __restrict__ flagsS,
    unsigned* __restrict__ AS, unsigned* __restrict__ N0S, unsigned* __restrict__ N1S,
    double* __restrict__ omS, unsigned* __restrict__ oflagsS)
{
    __shared__ unsigned short s_list[2048];
    __shared__ double s_part[16][64];
    __shared__ int s_kbc;

    const int wg = blockIdx.x;
    const int tid = threadIdx.x;
    const int wv = tid >> 6;
    const int lane = tid & 63;
    const bool isH = (wg < NWGH);

    const size_t rstride = isH ? (size_t)HN : (size_t)NOUTC;
    const int base0 = isH ? wg * 64 : (wg - NWGH) * 64;
    const float* gbase = (isH ? eff : wT) + base0 + lane;
    const int c = base0 + lane;            // wave-0 update column

    double colv = 0.0, hm = 0.0, om = 0.0, ffv = 0.0;
    float tauv = 0.f;
    int sp1 = 0, sp2 = 0, osp = 0;
    unsigned curA = 0, curN0 = 0, curN1 = 0, naccr = 0;
    if (wv == 0) {
        if (isH) { colv = colvH[c]; tauv = tau[c]; ffv = ff[c]; }
        else     { colv = colvO[c]; }
    }
    unsigned lsense = 0;
    int kcur = 0;
    unsigned myCnt = 0;

    for (int it = 0; it <= S_A; ++it) {
        const bool active = isH ? (it < S_A) : (it > 0);
        if (active) {
            const int k = kcur;
            const bool gspk = (k <= HN / 2);
            const int nlist = gspk ? k : HN - k;
            if (nlist > 0) {
                if (tid < 64) {
                    unsigned long long w = __hip_atomic_load(
                        &spk[(size_t)((it + 1) & 1) * 64 + lane],
                        __ATOMIC_RELAXED, __HIP_MEMORY_SCOPE_AGENT);
                    unsigned long long myw = gspk ? w : ~w;
                    int cnt = __popcll(myw);
                    int incl = cnt;
                    #pragma unroll
                    for (int d = 1; d < 64; d <<= 1) {
                        int o = __shfl_up(incl, d, 64);
                        if (lane >= d) incl += o;
                    }
                    int b = incl - cnt;
                    while (myw) {
                        int bp = __builtin_ctzll(myw);
                        s_list[b++] = (unsigned short)(lane * 64 + bp);
                        myw &= myw - 1;
                    }
                }
                __syncthreads();
                // 8-deep independent loads per iteration (latency hiding)
                double acc = 0.0;
                int idx = wv;
                for (; idx + 112 < nlist; idx += 128) {
                    const float v0 = gbase[(size_t)s_list[idx      ] * rstride];
                    const float v1 = gbase[(size_t)s_list[idx + 16 ] * rstride];
                    const float v2 = gbase[(size_t)s_list[idx + 32 ] * rstride];
                    const float v3 = gbase[(size_t)s_list[idx + 48 ] * rstride];
                    const float v4 = gbase[(size_t)s_list[idx + 64 ] * rstride];
                    const float v5 = gbase[(size_t)s_list[idx + 80 ] * rstride];
                    const float v6 = gbase[(size_t)s_list[idx + 96 ] * rstride];
                    const float v7 = gbase[(size_t)s_list[idx + 112] * rstride];
                    acc += (((double)v0 + (double)v1) + ((double)v2 + (double)v3))
                         + (((double)v4 + (double)v5) + ((double)v6 + (double)v7));
                }
                for (; idx < nlist; idx += 16)
                    acc += (double)gbase[(size_t)s_list[idx] * rstride];
                s_part[wv][lane] = acc;
                __syncthreads();
            }
            if (wv == 0) {
                double ssum = 0.0;
                if (nlist > 0) {
                    #pragma unroll
                    for (int p = 0; p < 16; ++p) ssum += s_part[p][lane];
                }
                double drive = gspk ? ssum : (colv - ssum);
                if (isH) {
                    const int t = it;
                    double cur = ffv + 0.1 * drive;
                    hm = hm * (double)tauv * (double)(1 - sp1) + cur;
                    int s = (hm >= 0.5) ? 1 : 0;
                    int n = s + sp1 + sp2;
                    sp2 = sp1; sp1 = s;
                    naccr += (unsigned)n;
                    unsigned bit = 1u << (t & 31);
                    if (s)     curA  |= bit;
                    if (n & 1) curN0 |= bit;
                    if (n & 2) curN1 |= bit;
                    unsigned long long ball = __ballot(s != 0);
                    if (lane == 0) {
                        __hip_atomic_store(&spk[(size_t)(t & 1) * 64 + wg], ball,
                                           __ATOMIC_RELEASE, __HIP_MEMORY_SCOPE_AGENT);
                        __threadfence();
                        myCnt = (unsigned)__popcll(ball);
                    }
                    ffv = ff[(size_t)(it + 1) * HN + c];  // prefetch (it+1<=S_A valid)
                } else {
                    const int t = it - 1;
                    om = om * 0.96 * (double)(1 - osp) + drive;
                    osp = (om >= 0.5) ? 1 : 0;
                    out[(size_t)t * NOUTC + c] = osp ? 1.0f : 0.0f;
                }
            }
        }
        if (it < S_A) {
            __syncthreads();
            if (tid == 0) {
                unsigned s = lsense ^ 1u;
                lsense = s;
                unsigned cntW = isH ? myCnt : 0u;
                unsigned long long prev = __hip_atomic_fetch_add(
                    &bar[0], (1ULL << 32) + (unsigned long long)cntW,
                    __ATOMIC_ACQ_REL, __HIP_MEMORY_SCOPE_AGENT);
                unsigned long long v;
                if ((unsigned)(prev >> 32) == NWGT - 1u) {
                    unsigned ktot = (unsigned)(prev & 0xffffffffULL) + cntW;
                    __hip_atomic_store(&bar[0], 0ULL, __ATOMIC_RELAXED, __HIP_MEMORY_SCOPE_AGENT);
                    v = ((unsigned long long)ktot << 1) | (unsigned long long)s;
                    __hip_atomic_store(&bar[1], v, __ATOMIC_RELEASE, __HIP_MEMORY_SCOPE_AGENT);
                } else {
                    int budget = 1 << 17;
                    for (;;) {
                        v = __hip_atomic_load(&bar[1], __ATOMIC_ACQUIRE, __HIP_MEMORY_SCOPE_AGENT);
                        if ((unsigned)(v & 1ULL) == s) break;
                        if (--budget == 0) break;
                    }
                }
                s_kbc = (int)(v >> 1);
            }
            __syncthreads();
            kcur = s_kbc;
        }
    }
    if (wv == 0) {
        if (isH) {
            hmS[c] = hm;
            flagsS[c] = (unsigned)sp1 | ((unsigned)sp2 << 1) | (naccr << 2);
            AS[c] = curA; N0S[c] = curN0; N1S[c] = curN1;
        } else {
            omS[c] = om;
            oflagsS[c] = (unsigned)osp;
        }
    }
}

// ---------------- K4b: single-WG adaptive scan, steps S_A..127 --------------
// Runs the general step until the OBSERVED spike count hits HN (all-spike) with
// satFail==0; from that step t_sw the closed form is exact (induction via the
// verified predicate). Handles any saturation time; falls back to fully
// general if saturation never observed.
__global__ __launch_bounds__(1024) void k_loopB(
    const float* __restrict__ eff, const float* __restrict__ wT,
    const double* __restrict__ ff, const float* __restrict__ tau,
    const double* __restrict__ colvH, const double* __restrict__ colvO,
    const unsigned long long* __restrict__ spk,
    const double* __restrict__ hmS, const unsigned* __restrict__ flagsS,
    const unsigned* __restrict__ AS, const unsigned* __restrict__ N0S,
    const unsigned* __restrict__ N1S,
    const double* __restrict__ omS, const unsigned* __restrict__ oflagsS,
    const unsigned* __restrict__ satFail,
    unsigned* __restrict__ AwP, unsigned* __restrict__ N0wP,
    unsigned* __restrict__ N1wP, unsigned* __restrict__ Nacc,
    float* __restrict__ out)
{
    __shared__ unsigned long long s_words[64];
    __shared__ unsigned short s_list[2048];

    const int tid = threadIdx.x;
    const int wv = tid >> 6, lane = tid & 63;

    // ---- load state (always) ----
    double hm[4], colv[4], tauv[4];
    unsigned curA[4], curN0[4], curN1[4], nacc[4];
    int sp1[4], sp2[4];
    #pragma unroll
    for (int p = 0; p < 4; ++p) {
        const int c = tid + 1024 * p;
        hm[p] = hmS[c];
        unsigned f = flagsS[c];
        sp1[p] = f & 1; sp2[p] = (f >> 1) & 1; nacc[p] = f >> 2;
        curA[p] = AS[c]; curN0[p] = N0S[c]; curN1[p] = N1S[c];
        tauv[p] = (double)tau[c];
        colv[p] = colvH[c];
    }
    double om = 0.0, colO = 0.0;
    int osp = 0;
    if (tid < NOUTC) {
        om = omS[tid]; osp = (int)(oflagsS[tid] & 1u);
        colO = colvO[tid];
    }

    // seed spikes from loopA's last step (parity (S_A-1)&1)
    if (tid < 64) s_words[tid] = spk[(size_t)((S_A - 1) & 1) * 64 + tid];
    __syncthreads();
    int kprev;
    {
        int v = __popcll(s_words[lane]);
        #pragma unroll
        for (int d = 1; d < 64; d <<= 1) v += __shfl_xor(v, d, 64);
        kprev = v;
    }
    bool gprev = (kprev <= HN / 2);
    int nprev = gprev ? kprev : HN - kprev;
    const bool satOK = (satFail[0] == 0u);
    bool allspike = (kprev == HN);

    if (nprev > 0) {
        if (tid < 64) {
            unsigned long long myw = gprev ? s_words[tid] : ~s_words[tid];
            int cnt = __popcll(myw), incl = cnt;
            #pragma unroll
            for (int d = 1; d < 64; d <<= 1) { int o = __shfl_up(incl, d, 64); if (lane >= d) incl += o; }
            int b = incl - cnt;
            while (myw) { int bp = __builtin_ctzll(myw); s_list[b++] = (unsigned short)(tid * 64 + bp); myw &= myw - 1; }
        }
        __syncthreads();
    }

    // ---- general loop until observed saturation ----
    int t = S_A;
    while (t < TT && !(satOK && allspike)) {
        double fcur[4];
        #pragma unroll
        for (int p = 0; p < 4; ++p) fcur[p] = ff[(size_t)t * HN + tid + 1024 * p];
        double drv[4];
        if (nprev > 0) {
            double s0 = 0.0, s1 = 0.0, s2 = 0.0, s3 = 0.0;
            for (int idx = 0; idx < nprev; ++idx) {
                const float* rp = eff + (size_t)s_list[idx] * HN + tid;
                s0 += (double)rp[0];
                s1 += (double)rp[1024];
                s2 += (double)rp[2048];
                s3 += (double)rp[3072];
            }
            drv[0] = gprev ? s0 : (colv[0] - s0);
            drv[1] = gprev ? s1 : (colv[1] - s1);
            drv[2] = gprev ? s2 : (colv[2] - s2);
            drv[3] = gprev ? s3 : (colv[3] - s3);
        } else {
            #pragma unroll
            for (int p = 0; p < 4; ++p) drv[p] = gprev ? 0.0 : colv[p];
        }
        int sb[4];
        const unsigned bit = 1u << (t & 31);
        #pragma unroll
        for (int p = 0; p < 4; ++p) {
            double cur = fcur[p] + 0.1 * drv[p];
            hm[p] = hm[p] * tauv[p] * (double)(1 - sp1[p]) + cur;
            sb[p] = (hm[p] >= 0.5) ? 1 : 0;
            int n = sb[p] + sp1[p] + sp2[p];
            sp2[p] = sp1[p]; sp1[p] = sb[p];
            nacc[p] += (unsigned)n;
            if (sb[p]) curA[p] |= bit;
            if (n & 1) curN0[p] |= bit;
            if (n & 2) curN1[p] |= bit;
        }
        if ((t & 31) == 31) {
            const int wq = t >> 5;
            #pragma unroll
            for (int p = 0; p < 4; ++p) {
                const int c = tid + 1024 * p;
                AwP [wq * HN + c] = curA[p];
                N0wP[wq * HN + c] = curN0[p];
                N1wP[wq * HN + c] = curN1[p];
                curA[p] = curN0[p] = curN1[p] = 0u;
            }
        }
        __syncthreads();
        #pragma unroll
        for (int p = 0; p < 4; ++p) {
            unsigned long long b = __ballot(sb[p] != 0);
            if (lane == 0) s_words[16 * p + wv] = b;
        }
        __syncthreads();
        int k;
        {
            int v = __popcll(s_words[lane]);
            #pragma unroll
            for (int d = 1; d < 64; d <<= 1) v += __shfl_xor(v, d, 64);
            k = v;
        }
        const bool gspk = (k <= HN / 2);
        const int nlist = gspk ? k : HN - k;
        if (nlist > 0) {
            if (tid < 64) {
                unsigned long long myw = gspk ? s_words[tid] : ~s_words[tid];
                int cnt = __popcll(myw), incl = cnt;
                #pragma unroll
                for (int d = 1; d < 64; d <<= 1) { int o = __shfl_up(incl, d, 64); if (lane >= d) incl += o; }
                int b2 = incl - cnt;
                while (myw) { int bp = __builtin_ctzll(myw); s_list[b2++] = (unsigned short)(tid * 64 + bp); myw &= myw - 1; }
            }
            __syncthreads();
        }
        if (tid < NOUTC) {
            double so = 0.0;
            for (int idx = 0; idx < nlist; ++idx)
                so += (double)wT[(size_t)s_list[idx] * NOUTC + tid];
            double drv_o = gspk ? so : (colO - so);
            om = om * 0.96 * (double)(1 - osp) + drv_o;
            osp = (om >= 0.5) ? 1 : 0;
            out[(size_t)t * NOUTC + tid] = osp ? 1.0f : 0.0f;
        }
        gprev = gspk; nprev = nlist;
        allspike = (k == HN);
        ++t;
    }

    if (t < TT) {
        // ---- closed-form tail from t_sw = t (sp1[p]==1 for all neurons) ----
        const int t_sw = t;
        const int wq_sw = t_sw >> 5;
        const int off = t_sw & 31;
        const unsigned hiA = 0xFFFFFFFFu << off;
        const unsigned hi1 = (off < 31) ? (0xFFFFFFFFu << (off + 1)) : 0u;
        #pragma unroll
        for (int p = 0; p < 4; ++p) {
            const int c = tid + 1024 * p;
            AwP [wq_sw * HN + c] = curA[p]  | hiA;
            N0wP[wq_sw * HN + c] = curN0[p] | ((unsigned)sp2[p] << off) | hi1;
            N1wP[wq_sw * HN + c] = curN1[p] | hiA;
            for (int wq = wq_sw + 1; wq < 4; ++wq) {
                AwP [wq * HN + c] = 0xFFFFFFFFu;
                N0wP[wq * HN + c] = 0xFFFFFFFFu;
                N1wP[wq * HN + c] = 0xFFFFFFFFu;
            }
            Nacc[c] = nacc[p] + (unsigned)(2 + sp2[p]) + 3u * (unsigned)(TT - 1 - t_sw);
        }
        if (tid < NOUTC) {
            for (int tt = t_sw; tt < TT; ++tt) {
                om = om * 0.96 * (double)(1 - osp) + colO;
                osp = (om >= 0.5) ? 1 : 0;
                out[(size_t)tt * NOUTC + tid] = osp ? 1.0f : 0.0f;
            }
        }
        return;
    }
    #pragma unroll
    for (int p = 0; p < 4; ++p) Nacc[tid + 1024 * p] = nacc[p];
}

// ---------------- K5: rec_out = recurrent + 0.01*(3T - 2N[i] + 2M[i][j]) ----
__global__ __launch_bounds__(256) void k_rec(const float* __restrict__ recur,
    const unsigned* __restrict__ AwP, const unsigned* __restrict__ N0wP,
    const unsigned* __restrict__ N1wP, const unsigned* __restrict__ Nacc,
    float* __restrict__ out)
{
    const int j = blockIdx.x * 256 + threadIdx.x;
    const int i0 = blockIdx.y * 32;
    const unsigned a0 = AwP[0 * HN + j], a1 = AwP[1 * HN + j];
    const unsigned a2 = AwP[2 * HN + j], a3 = AwP[3 * HN + j];
    for (int ii = 0; ii < 32; ++ii) {
        const int i = i0 + ii;
        const unsigned n00 = N0wP[0 * HN + i], n01 = N0wP[1 * HN + i];
        const unsigned n02 = N0wP[2 * HN + i], n03 = N0wP[3 * HN + i];
        const unsigned n10 = N1wP[0 * HN + i], n11 = N1wP[1 * HN + i];
        const unsigned n12 = N1wP[2 * HN + i], n13 = N1wP[3 * HN + i];
        int M = __popc(a0 & n00) + __popc(a1 & n01) + __popc(a2 & n02) + __popc(a3 & n03);
        M += 2 * (__popc(a0 & n10) + __popc(a1 & n11) + __popc(a2 & n12) + __popc(a3 & n13));
        const int D = 3 * TT - 2 * (int)Nacc[i] + 2 * M;
        out[(size_t)i * HN + j] = (float)((double)recur[(size_t)i * HN + j] + 0.01 * (double)D);
    }
}

// ---------------- host ------------------------------------------------------
extern "C" void kernel_launch(void* const* d_in, const int* in_sizes, int n_in,
                              void* d_out, int out_size, void* d_ws, size_t ws_size,
                              hipStream_t stream) {
    const float* x         = (const float*)d_in[0];
    const float* w_fc1     = (const float*)d_in[1];
    const float* w_out     = (const float*)d_in[2];
    const float* recurrent = (const float*)d_in[3];
    const float* tau       = (const float*)d_in[4];
    const float* binary    = (const float*)d_in[6];
    float* out = (float*)d_out;
    float* rec_out = out + (size_t)TT * NOUTC;   // [HN,HN] region of d_out
    float* eff = rec_out;                         // reused as eff_rec scratch

    char* ws = (char*)d_ws;
    size_t off = 0;
    float* wT  = (float*)(ws + off);                 off += (size_t)HN * NOUTC * 4;   // 4MB
    double* ff = (double*)(ws + off);                off += (size_t)TT * HN * 8;      // 4MB
    // zero-span (contiguous): spk, bar(+satFail)
    unsigned long long* spk = (unsigned long long*)(ws + off); off += 2 * 64 * 8;     // 1KB
    unsigned long long* bar = (unsigned long long*)(ws + off); off += 256;
    unsigned* satFail = (unsigned*)((char*)bar + 128);   // inside zeroed bar block
    const int zwords = (int)((2 * 64 * 8 + 256) / 4);
    unsigned* AwP  = (unsigned*)(ws + off);          off += (size_t)4 * HN * 4;       // 64KB
    unsigned* N0wP = (unsigned*)(ws + off);          off += (size_t)4 * HN * 4;
    unsigned* N1wP = (unsigned*)(ws + off);          off += (size_t)4 * HN * 4;
    unsigned* Nacc = (unsigned*)(ws + off);          off += (size_t)HN * 4;
    double* colP   = (double*)(ws + off);            off += (size_t)NRB * HN * 8;     // 2MB
    double* colvH  = (double*)(ws + off);            off += (size_t)HN * 8;           // 32KB
    double* colvO  = (double*)(ws + off);            off += (size_t)NOUTC * 8;        // 2KB
    // A→B handoff state
    double*   hmS    = (double*)(ws + off);          off += (size_t)HN * 8;           // 32KB
    unsigned* flagsS = (unsigned*)(ws + off);        off += (size_t)HN * 4;           // 16KB
    unsigned* AS     = (unsigned*)(ws + off);        off += (size_t)HN * 4;
    unsigned* N0S    = (unsigned*)(ws + off);        off += (size_t)HN * 4;
    unsigned* N1S    = (unsigned*)(ws + off);        off += (size_t)HN * 4;
    double*   omS    = (double*)(ws + off);          off += (size_t)NOUTC * 8;        // 2KB
    unsigned* oflagsS= (unsigned*)(ws + off);        off += (size_t)NOUTC * 4;        // 1KB

    if (ws_size < off) return;  // refuse to corrupt memory if scratch too small

    k_pre<<<dim3(4, 64), dim3(256), 0, stream>>>(
        (const float4*)recurrent, (const float4*)binary,
        (float4*)eff, colP, (unsigned*)spk, zwords);
    k_misc<<<dim3(320), dim3(256), 0, stream>>>(w_out, wT, colvO);
    k_ff<<<dim3(64, 8), dim3(256), 0, stream>>>(x, w_fc1, ff);
    k_colred<<<dim3(16), dim3(256), 0, stream>>>(colP, colvH);
    k_sat<<<dim3(TT - S_A), dim3(256), 0, stream>>>(ff, colvH, satFail);
    k_loopA<<<dim3(NWGT), dim3(1024), 0, stream>>>(eff, wT, ff, tau, colvH, colvO,
                                                   spk, bar, out,
                                                   hmS, flagsS, AS, N0S, N1S, omS, oflagsS);
    k_loopB<<<dim3(1), dim3(1024), 0, stream>>>(eff, wT, ff, tau, colvH, colvO, spk,
                                                hmS, flagsS, AS, N0S, N1S, omS, oflagsS,
                                                satFail, AwP, N0wP, N1wP, Nacc, out);
    k_rec<<<dim3(16, 128), dim3(256), 0, stream>>>(recurrent, AwP, N0wP, N1wP, Nacc,
                                                   rec_out);
}